// Round 3
// baseline (333.118 us; speedup 1.0000x reference)
//
#include <hip/hip_runtime.h>
#include <hip/hip_bf16.h>

// Correlation (FlowNet): out[b, 21*ky+kx, i, j] = (1/C) sum_c in1[b,c,i,j] * in2[b,c,i+2ky-20,j+2kx-20]
// Parity split j=2u+pj -> banded Gram G[u,w]=sum_c X[c,u]Y[c,w], w=u+kx-10, via 32x32x16 bf16 MFMA.
// BISECT ROUND: 32x32 MFMA kept; staging reverted to round-1-verified reg-staged ds_write + linear repack.

#define NB 8
#define NC 256
#define NH 96
#define NW 128
#define NU 64
#define ND 21
#define NK 441
#define HW (NH * NW)

typedef __attribute__((ext_vector_type(8))) short s16x8;
typedef __attribute__((ext_vector_type(16))) float f32x16;

__device__ __forceinline__ unsigned short f2bf(float f) {
    unsigned int x = __float_as_uint(f);
    x += 0x7fffu + ((x >> 16) & 1u);   // RTNE
    return (unsigned short)(x >> 16);
}

// ---------------- prepass (round-1-verified mechanics, in2 only):
// fp32 [b][c][r][j] -> bf16 yg[b][pj][r][u][c]  (linear, no pre-swizzle)
__global__ __launch_bounds__(256) void repack3(
    const float* __restrict__ in2, unsigned short* __restrict__ yg)
{
    int bid = blockIdx.x;
    int ct = bid & 3;                  // c-tile of 64
    int rest = bid >> 2;
    int r = rest % NH;
    int b = rest / NH;
    int c0 = ct * 64;

    __shared__ unsigned short tbuf[128][68];   // [j][c_local], +4 pad

    int tid = threadIdx.x;
    int j = tid & 127;
    int ch = tid >> 7;
    #pragma unroll 4
    for (int p = 0; p < 32; ++p) {
        int cl = p * 2 + ch;
        tbuf[j][cl] = f2bf(in2[(((size_t)b * NC + (c0 + cl)) * NH + r) * NW + j]);
    }
    __syncthreads();
    int c2 = tid & 31;
    int jr = tid >> 5;
    #pragma unroll
    for (int jj0 = 0; jj0 < 128; jj0 += 8) {
        int jj = jj0 + jr;
        int pj = jj & 1, u = jj >> 1;
        unsigned int val = *reinterpret_cast<const unsigned int*>(&tbuf[jj][2 * c2]);
        size_t o = ((((size_t)b * 2 + pj) * NH + r) * NU + u) * NC + c0 + 2 * c2;
        *reinterpret_cast<unsigned int*>(&yg[o]) = val;
    }
}

// ---------------- main kernel ----------------
// LDS: Y[128 rows(pj,u)][512B] swizzled | G[128][55] f32 | 16B zero
#define GOFF 65536
#define GPITCH 55
#define ZOFF (GOFF + 128 * GPITCH * 4)   // 93696
#define LDSZ (ZOFF + 16)

__global__ __launch_bounds__(512, 2) void corr32r(
    const float* __restrict__ in1,
    const unsigned short* __restrict__ yg,
    float* __restrict__ out)
{
    __shared__ __align__(16) unsigned char LDS[LDSZ];

    int bid = blockIdx.x;
    int b = bid & 7;           // XCD-grouped
    int i = bid >> 3;
    int tid = threadIdx.x;
    int lane = tid & 63;
    int wv = tid >> 6;         // 8 waves: (pj, ut, wt)
    int pj = wv >> 2;
    int ut = (wv >> 1) & 1;
    int wt = wv & 1;
    int l31 = lane & 31;
    int hp = lane >> 5;

    if (tid == 0) { *reinterpret_cast<uint4*>(&LDS[ZOFF]) = uint4{0u, 0u, 0u, 0u}; }

    int ky0 = 21 - i; ky0 = (ky0 > 0) ? (ky0 >> 1) : 0;
    int ky1 = (115 - i) >> 1; if (ky1 > 20) ky1 = 20;
    int r0 = i + 2 * ky0 - 20;

    const unsigned short* ygb = yg + (size_t)b * 2 * NH * NU * NC;

    // issue Y(r0) loads -> regs (8 x uint4 per thread)
    uint4 stg[8];
    #pragma unroll
    for (int m = 0; m < 8; ++m) {
        int idx = m * 512 + tid;           // 0..4095
        int rho = idx >> 5, o32 = idx & 31;
        int ps = rho >> 6, u = rho & 63;
        stg[m] = *reinterpret_cast<const uint4*>(
            ygb + ((size_t)ps * NH + r0) * (NU * NC) + u * NC + o32 * 8);
    }

    // ---- A fragments: register-resident, direct from fp32 in1 ----
    int u_a = ut * 32 + l31;
    int j_a = 2 * u_a + pj;
    const float* arow = in1 + (((size_t)b * NC) * NH + i) * NW + j_a;
    s16x8 afr[16];
    #pragma unroll
    for (int ks = 0; ks < 16; ++ks) {
        int c0 = ks * 16 + hp * 8;
        s16x8 a;
        #pragma unroll
        for (int s = 0; s < 8; ++s) a[s] = (short)f2bf(arow[(size_t)(c0 + s) * HW]);
        afr[ks] = a;
    }

    // write Y(r0) to LDS (swizzle applied at write time — round-1 mechanics)
    #pragma unroll
    for (int m = 0; m < 8; ++m) {
        int idx = m * 512 + tid;
        int rho = idx >> 5, o32 = idx & 31;
        int u = rho & 63;
        *reinterpret_cast<uint4*>(&LDS[rho * 512 + ((o32 * 16) ^ ((u & 7) << 4))]) = stg[m];
    }

    // zero-fill invalid ky
    int jx = tid & 127;
    int kq = tid >> 7;
    for (int ky = 0; ky < ky0; ++ky) {
        size_t ob = (((size_t)b * NK + 21 * ky) * NH + i) * NW + jx;
        for (int kx = kq; kx < ND; kx += 4) out[ob + (size_t)kx * HW] = 0.0f;
    }
    for (int ky = ky1 + 1; ky <= 20; ++ky) {
        size_t ob = (((size_t)b * NK + 21 * ky) * NH + i) * NW + jx;
        for (int kx = kq; kx < ND; kx += 4) out[ob + (size_t)kx * HW] = 0.0f;
    }

    // B row addressing (ky-invariant)
    int w = ut * 32 - 10 + wt * 32 + l31;
    bool bval = (w >= 0) && (w < NU);
    int rowbase = (pj * 64 + w) * 512;   // only used when bval
    int wsw = (w & 7) << 4;

    // extract addressing (ky-invariant)
    int ue = jx >> 1;
    int gerow = ((jx & 1) * 2 + (ue >> 5)) * 32 + (ue & 31);
    const int gebase = GOFF + (gerow * GPITCH + (ue & 31)) * 4;

    int grow0 = (pj * 2 + ut) * 32;
    int col = wt * 32 + l31;

    for (int ky = ky0; ky <= ky1; ++ky) {
        __syncthreads();               // B1: Y(ky) visible; G(ky-1) reads done

        if (ky < ky1) {                // issue Y(ky+1) loads early (latency under MFMA)
            int r2 = i + 2 * ky - 18;
            #pragma unroll
            for (int m = 0; m < 8; ++m) {
                int idx = m * 512 + tid;
                int rho = idx >> 5, o32 = idx & 31;
                int ps = rho >> 6, u = rho & 63;
                stg[m] = *reinterpret_cast<const uint4*>(
                    ygb + ((size_t)ps * NH + r2) * (NU * NC) + u * NC + o32 * 8);
            }
        }

        f32x16 acc;
        #pragma unroll
        for (int z = 0; z < 16; ++z) acc[z] = 0.0f;
        #pragma unroll
        for (int k8 = 0; k8 < 16; ++k8) {
            int off = k8 * 32 + hp * 16;
            int a0 = bval ? (rowbase + (off ^ wsw)) : ZOFF;
            s16x8 bf = *reinterpret_cast<const s16x8*>(&LDS[a0]);
            acc = __builtin_amdgcn_mfma_f32_32x32x16_bf16(afr[k8], bf, acc, 0, 0, 0);
        }

        // spill G (only live cols < 52): D layout col=lane&31, row=(reg&3)+8*(reg>>2)+4*(lane>>5)
        if (col < 52) {
            #pragma unroll
            for (int r16 = 0; r16 < 16; ++r16) {
                int ur = (r16 & 3) + 8 * (r16 >> 2) + 4 * hp;
                *reinterpret_cast<float*>(
                    &LDS[GOFF + ((grow0 + ur) * GPITCH + col) * 4]) = acc[r16];
            }
        }
        __syncthreads();               // B2: Y(ky) reads done; G visible

        if (ky < ky1) {                // write Y(ky+1) from staged regs
            #pragma unroll
            for (int m = 0; m < 8; ++m) {
                int idx = m * 512 + tid;
                int rho = idx >> 5, o32 = idx & 31;
                int u = rho & 63;
                *reinterpret_cast<uint4*>(
                    &LDS[rho * 512 + ((o32 * 16) ^ ((u & 7) << 4))]) = stg[m];
            }
        }

        // band extraction + coalesced store
        size_t ob = (((size_t)b * NK + 21 * ky) * NH + i) * NW + jx;
        for (int kx = kq; kx < ND; kx += 4) {
            out[ob + (size_t)kx * HW] =
                *reinterpret_cast<const float*>(&LDS[gebase + kx * 4]) * 0.00390625f;
        }
    }
}

// ---------------- fallback (ws too small): 1 thread per output ----------------
__global__ __launch_bounds__(256) void corr_naive(
    const float* __restrict__ in1, const float* __restrict__ in2, float* __restrict__ out)
{
    size_t o = (size_t)blockIdx.x * 256 + threadIdx.x;
    if (o >= (size_t)NB * NK * NH * NW) return;
    int j = o & 127;
    int i = (int)((o >> 7) % NH);
    size_t rest = o / ((size_t)NH * NW);
    int k = (int)(rest % NK);
    int b = (int)(rest / NK);
    int ky = k / ND, kx = k % ND;
    int r = i + 2 * ky - 20, jc = j + 2 * kx - 20;
    float s = 0.f;
    if (r >= 0 && r < NH && jc >= 0 && jc < NW) {
        const float* p1 = in1 + (((size_t)b * NC) * NH + i) * NW + j;
        const float* p2 = in2 + (((size_t)b * NC) * NH + r) * NW + jc;
        for (int c = 0; c < NC; ++c) { s += p1[0] * p2[0]; p1 += NH * NW; p2 += NH * NW; }
    }
    out[o] = s * (1.0f / 256.0f);
}

extern "C" void kernel_launch(void* const* d_in, const int* in_sizes, int n_in,
                              void* d_out, int out_size, void* d_ws, size_t ws_size,
                              hipStream_t stream) {
    const float* in1 = (const float*)d_in[0];
    const float* in2 = (const float*)d_in[1];
    float* out = (float*)d_out;

    const size_t need = (size_t)NB * 2 * NH * NU * NC * sizeof(unsigned short);  // ~50.3 MB

    if (ws_size < need) {
        size_t total = (size_t)NB * NK * NH * NW;
        corr_naive<<<(int)((total + 255) / 256), 256, 0, stream>>>(in1, in2, out);
        return;
    }

    unsigned short* yg = (unsigned short*)d_ws;

    repack3<<<NB * NH * 4, 256, 0, stream>>>(in2, yg);
    corr32r<<<NB * NH, 512, 0, stream>>>(in1, yg, out);
}